// Round 8
// baseline (538.255 us; speedup 1.0000x reference)
//
#include <hip/hip_runtime.h>

// LSTM B=2048, T=1024, H=50. Round 21: two-group phase interleave (R20 idea)
// with a correct LDS budget (R20 overflowed 64 KiB static shared: 74 KB).
//  - Each block owns TWO independent batch groups of FOUR batches
//    (A: b0..b0+3, B: b0+4..b0+7). Phases alternate A,B,A,B with one barrier
//    per phase. Right after the barrier that publishes group X's h, group X's
//    next-step ds_read is issued; it lands while the OTHER group's
//    MFMA+epilogue runs -> h-read latency and barrier resync leave the
//    critical chain.
//  - B cols = 4 batches x 4 replica groups. Lane (kq, rep=L15>>2, bl=L15&3):
//    unit j = 8w + 4*(rep&1) + kq; tile select = rep&1. Lanes rep>=2
//    duplicate rep-2 (same acc, same h) and are masked off the LDS write.
//  - Weights shared between groups (A-fragments, zw/zb); only B-fragments,
//    c2, h, x duplicate.
//  - LDS: hb 2*2*4*80*2 = 2.5 KB, XT[1026][8] f32 = 32.8 KB, redH 1.6 KB
//    -> ~37 KB (same as every proven config). grid=256, 1 block/CU, 7 waves.
//  - Keeps R18 wins: zc C-operand init (exact f32 gx), chained split-K,
//    exp2-only epilogue, pre-scaled c2 = 2*log2e*c, KP=80.

#define H     50
#define TT    1024
#define BATCH 2048
#define BW    4      // batches per group
#define NG    2      // phase-interleaved groups per block
#define NTHR  448    // 7 waves
#define KP    80     // f16 per hb row (40-word stride, measured conflict-free)

typedef float    f32x4 __attribute__((ext_vector_type(4)));
typedef _Float16 f16x8 __attribute__((ext_vector_type(8)));

__global__ __launch_bounds__(NTHR, 1) void lstm_kernel(
    const float* __restrict__ x,      // [B, T]
    const float* __restrict__ W_ih,   // [200]
    const float* __restrict__ W_hh,   // [200, 50]
    const float* __restrict__ b_ih,   // [200]
    const float* __restrict__ b_hh,   // [200]
    const float* __restrict__ W_lin,  // [50]
    const float* __restrict__ b_lin,  // [1]
    float* __restrict__ out)          // [B]
{
    __shared__ _Float16 hb[NG][2][BW][KP];   // h^T per group, double-buffered
    __shared__ float    XT[TT + 2][NG * BW]; // x per (t, batch), +2 pad rows
    __shared__ float    redH[H][NG * BW];    // head reduction

    const int tid  = threadIdx.x;
    const int wave = tid >> 6;
    const int lane = tid & 63;
    const int L15  = lane & 15;
    const int kq   = lane >> 4;
    const int bl   = L15 & 3;             // batch within group
    const int rep  = L15 >> 2;            // replica group 0..3
    const int b0   = blockIdx.x * (NG * BW);

    const int t0 = 2 * wave;              // tiles t0, t0+1 (wave 6: 12,13)

    const float LOG2E  = 1.4426950408889634f;
    const float LOG2E2 = 2.8853900817779268f;

    // ---- A fragments: scaled permuted W_hh rows (k 0..49), f16; shared ----
    f16x8 A[2][2];
    #pragma unroll
    for (int tt = 0; tt < 2; ++tt) {
        const int m  = (t0 + tt) * 16 + L15;  // permuted gate-row n' = 4j+g
        const int jm = m >> 2, gm = m & 3;
        const bool v = (jm < H);
        const float s = (gm == 2) ? LOG2E2 : -LOG2E;
        #pragma unroll
        for (int kf = 0; kf < 2; ++kf) {
            f16x8 vv;
            #pragma unroll
            for (int e = 0; e < 8; ++e) {
                const int k = kf * 32 + kq * 8 + e;
                _Float16 val = (_Float16)0.f;
                if (v && k < H) val = (_Float16)(s * W_hh[(gm * H + jm) * H + k]);
                vv[e] = val;
            }
            A[tt][kf] = vv;
        }
    }

    // ---- this lane's unit + exact f32 x-path coefficients (shared) ----
    const int  j  = 8 * wave + 4 * (rep & 1) + kq;   // 0..55 (50-55 pad)
    const bool jv = (j < H);
    const bool wr = (L15 < 8);                       // rep 0,1: unique writer
    const float wlin = jv ? W_lin[j] : 0.f;
    float zw[4], zb[4];
    #pragma unroll
    for (int r = 0; r < 4; ++r) {
        const float s = (r == 2) ? LOG2E2 : -LOG2E;
        zw[r] = jv ? s * W_ih[r * H + j] : 0.f;
        zb[r] = jv ? s * (b_ih[r * H + j] + b_hh[r * H + j]) : 0.f;
    }

    // ---- init: zero hb; fill XT (coalesced in t; 8 batches) ----
    for (int i = tid; i < NG * 2 * BW * KP; i += NTHR)
        ((_Float16*)hb)[i] = (_Float16)0.f;
    for (int i = tid; i < TT * NG * BW; i += NTHR) {
        const int bb = i >> 10, t = i & 1023;
        XT[t][bb] = x[(size_t)(b0 + bb) * TT + t];
    }
    if (tid < 2 * NG * BW) ((float*)&XT[TT][0])[tid] = 0.f;  // pad rows

    float c2A = 0.f, c2B = 0.f;        // scaled cell states (2*log2e*c)
    float hAf = 0.f, hBf = 0.f;
    __syncthreads();

    f16x8 fA0 = {};                    // h_A(-1) = 0 fragments (pre-loaded)
    f16x8 fA1 = {};
    float xA = XT[0][bl];
    float xB = XT[0][BW + bl];
    const bool lo = ((rep & 1) == 0);  // tile select

    #pragma unroll 1
    for (int tbase = 0; tbase < TT; tbase += 2) {
        #pragma unroll
        for (int p = 0; p < 2; ++p) {
            const int t = tbase + p;

            // ---- prefetch group-B frags (h_B(t-1): published >=1 barrier
            //      ago); lands during phase A's compute ----
            const _Float16* hpB = &hb[1][p][bl][0];
            const f16x8 fB0 = *(const f16x8*)(hpB + kq * 8);
            const f16x8 fB1 = *(const f16x8*)(hpB + 32 + kq * 8);

            // ================= PHASE A (step t, group A) =================
            {
                f32x4 zc;
                #pragma unroll
                for (int r = 0; r < 4; ++r)
                    zc[r] = __builtin_fmaf(zw[r], xA, zb[r]);

                f32x4 a0 = __builtin_amdgcn_mfma_f32_16x16x32_f16(A[0][0], fA0, zc, 0, 0, 0);
                f32x4 a1 = __builtin_amdgcn_mfma_f32_16x16x32_f16(A[1][0], fA0, zc, 0, 0, 0);
                a0 = __builtin_amdgcn_mfma_f32_16x16x32_f16(A[0][1], fA1, a0, 0, 0, 0);
                a1 = __builtin_amdgcn_mfma_f32_16x16x32_f16(A[1][1], fA1, a1, 0, 0, 0);

                xA = XT[t + 1][bl];               // next x (off-chain)

                const float gi = lo ? a0[0] : a1[0];
                const float gf = lo ? a0[1] : a1[1];
                const float gg = lo ? a0[2] : a1[2];
                const float go = lo ? a0[3] : a1[3];

                const float Ei = __builtin_amdgcn_exp2f(gi);
                const float Ef = __builtin_amdgcn_exp2f(gf);
                const float Eg = __builtin_amdgcn_exp2f(gg);
                const float Eo = __builtin_amdgcn_exp2f(go);
                const float P  = (1.0f + Ei) * (1.0f + Eg);
                const float Q2 = __builtin_fmaf(LOG2E2, Ef, LOG2E2);
                const float num = __builtin_fmaf(c2A, P, (Eg - 1.0f) * Q2);
                const float PQ  = P * (1.0f + Ef);
                c2A = num * __builtin_amdgcn_rcpf(PQ);
                const float ca = fminf(c2A, 80.0f);
                const float Ec = __builtin_amdgcn_exp2f(ca);
                hAf = (Ec - 1.0f) *
                    __builtin_amdgcn_rcpf((1.0f + Eo) * (1.0f + Ec));

                if (wr) (&hb[0][p ^ 1][bl][0])[j] = (_Float16)hAf;  // pads self-zero
            }
            __syncthreads();

            // ---- prefetch group-A frags for step t+1 (h_A(t), just
            //      published); lands during phase B's compute ----
            const _Float16* hpA = &hb[0][p ^ 1][bl][0];
            const f16x8 nA0 = *(const f16x8*)(hpA + kq * 8);
            const f16x8 nA1 = *(const f16x8*)(hpA + 32 + kq * 8);

            // ================= PHASE B (step t, group B) =================
            {
                f32x4 zc;
                #pragma unroll
                for (int r = 0; r < 4; ++r)
                    zc[r] = __builtin_fmaf(zw[r], xB, zb[r]);

                f32x4 a0 = __builtin_amdgcn_mfma_f32_16x16x32_f16(A[0][0], fB0, zc, 0, 0, 0);
                f32x4 a1 = __builtin_amdgcn_mfma_f32_16x16x32_f16(A[1][0], fB0, zc, 0, 0, 0);
                a0 = __builtin_amdgcn_mfma_f32_16x16x32_f16(A[0][1], fB1, a0, 0, 0, 0);
                a1 = __builtin_amdgcn_mfma_f32_16x16x32_f16(A[1][1], fB1, a1, 0, 0, 0);

                xB = XT[t + 1][BW + bl];          // next x (off-chain)

                const float gi = lo ? a0[0] : a1[0];
                const float gf = lo ? a0[1] : a1[1];
                const float gg = lo ? a0[2] : a1[2];
                const float go = lo ? a0[3] : a1[3];

                const float Ei = __builtin_amdgcn_exp2f(gi);
                const float Ef = __builtin_amdgcn_exp2f(gf);
                const float Eg = __builtin_amdgcn_exp2f(gg);
                const float Eo = __builtin_amdgcn_exp2f(go);
                const float P  = (1.0f + Ei) * (1.0f + Eg);
                const float Q2 = __builtin_fmaf(LOG2E2, Ef, LOG2E2);
                const float num = __builtin_fmaf(c2B, P, (Eg - 1.0f) * Q2);
                const float PQ  = P * (1.0f + Ef);
                c2B = num * __builtin_amdgcn_rcpf(PQ);
                const float ca = fminf(c2B, 80.0f);
                const float Ec = __builtin_amdgcn_exp2f(ca);
                hBf = (Ec - 1.0f) *
                    __builtin_amdgcn_rcpf((1.0f + Eo) * (1.0f + Ec));

                if (wr) (&hb[1][p ^ 1][bl][0])[j] = (_Float16)hBf;
            }
            __syncthreads();

            fA0 = nA0;                 // register rotation (renamed by unroll)
            fA1 = nA1;
        }
    }

    // ---- head: out[b] = b_lin + sum_j W_lin[j] * h[j][b], both groups ----
    if (jv && wr) {
        redH[j][bl]      = wlin * hAf;
        redH[j][BW + bl] = wlin * hBf;
    }
    __syncthreads();
    if (tid < NG * BW) {
        float s = b_lin[0];
        #pragma unroll 10
        for (int jj = 0; jj < H; ++jj) s += redH[jj][tid];
        out[b0 + tid] = s;
    }
}

extern "C" void kernel_launch(void* const* d_in, const int* in_sizes, int n_in,
                              void* d_out, int out_size, void* d_ws, size_t ws_size,
                              hipStream_t stream) {
    const float* x     = (const float*)d_in[0];
    const float* W_ih  = (const float*)d_in[1];
    const float* W_hh  = (const float*)d_in[2];
    const float* b_ih  = (const float*)d_in[3];
    const float* b_hh  = (const float*)d_in[4];
    const float* W_lin = (const float*)d_in[5];
    const float* b_lin = (const float*)d_in[6];
    float* out = (float*)d_out;

    dim3 grid(BATCH / (NG * BW));   // 256 blocks, 1 per CU
    dim3 block(NTHR);               // 7 waves
    lstm_kernel<<<grid, block, 0, stream>>>(x, W_ih, W_hh, b_ih, b_hh,
                                            W_lin, b_lin, out);
}

// Round 9
// 462.308 us; speedup vs baseline: 1.1643x; 1.1643x over previous
//
#include <hip/hip_runtime.h>

// LSTM B=2048, T=1024, H=50. Round 22: R18 skeleton at BW=4 with TWO blocks
// co-resident per CU (grid=512). R15-vs-R19 showed a sibling block fills a
// block's barrier dead-time (~250 cy/step: drain + arrival skew + post-barrier
// LDS read burst) because the two blocks' barriers phase-slip independently.
// R21 localized the step cost: read-exposure ~70cy, chain ~330cy, barrier
// ~250-300cy -> donate the barrier dead-time to a sibling.
//  - 7 waves, BW=4: B cols = 4 batches (bl=L15&3) x 4 replicas (rep=L15>>2).
//    Lane's unit j = 8w + 4*(rep&1) + kq; lanes L15>=8 are duplicates and are
//    write-masked. 1 epilogue/lane (same chain as R18).
//  - LDS per block ~18.5 KB (XT[1026][4] 16.4K + hb 1.25K + redH 0.8K):
//    two blocks fit one CU trivially.
//  - Everything else IS R18: chained split-K MFMA, zc C-operand init (exact
//    f32 gx, prefetched x), exp2-only epilogue, pre-scaled c2 = 2*log2e*c,
//    KP=80, one barrier per step, x2 unrolled halves, pads self-zero.

#define H     50
#define TT    1024
#define BATCH 2048
#define BW    4
#define NTHR  448     // 7 waves
#define KP    80      // f16 per hb row (40-word stride, measured conflict-free)

typedef float    f32x4 __attribute__((ext_vector_type(4)));
typedef _Float16 f16x8 __attribute__((ext_vector_type(8)));

__global__ __launch_bounds__(NTHR, 1) void lstm_kernel(
    const float* __restrict__ x,      // [B, T]
    const float* __restrict__ W_ih,   // [200]
    const float* __restrict__ W_hh,   // [200, 50]
    const float* __restrict__ b_ih,   // [200]
    const float* __restrict__ b_hh,   // [200]
    const float* __restrict__ W_lin,  // [50]
    const float* __restrict__ b_lin,  // [1]
    float* __restrict__ out)          // [B]
{
    __shared__ _Float16 hb[2][BW][KP];    // h^T, double-buffered
    __shared__ float    XT[TT + 2][BW];   // x per (t, b), +2 pad rows
    __shared__ float    redH[H][BW];      // head reduction

    const int tid  = threadIdx.x;
    const int wave = tid >> 6;
    const int lane = tid & 63;
    const int L15  = lane & 15;
    const int kq   = lane >> 4;
    const int bl   = L15 & 3;             // batch within block
    const int sel  = (L15 >> 2) & 1;      // tile-select bit
    const int b0   = blockIdx.x * BW;

    const int t0 = 2 * wave;              // tiles t0, t0+1 (wave 6: 12,13)

    const float LOG2E  = 1.4426950408889634f;
    const float LOG2E2 = 2.8853900817779268f;

    // ---- A fragments: scaled permuted W_hh rows (k 0..49 only), f16 ----
    f16x8 A[2][2];
    #pragma unroll
    for (int tt = 0; tt < 2; ++tt) {
        const int m  = (t0 + tt) * 16 + L15;  // permuted gate-row n' = 4j+g
        const int jm = m >> 2, gm = m & 3;
        const bool v = (jm < H);
        const float s = (gm == 2) ? LOG2E2 : -LOG2E;
        #pragma unroll
        for (int kf = 0; kf < 2; ++kf) {
            f16x8 vv;
            #pragma unroll
            for (int e = 0; e < 8; ++e) {
                const int k = kf * 32 + kq * 8 + e;
                _Float16 val = (_Float16)0.f;
                if (v && k < H) val = (_Float16)(s * W_hh[(gm * H + jm) * H + k]);
                vv[e] = val;
            }
            A[tt][kf] = vv;
        }
    }

    // ---- this lane's unit + exact f32 x-path coefficients (C-init) ----
    const int  j  = 8 * wave + 4 * sel + kq;     // 0..55 (50-55 pad)
    const bool jv = (j < H);
    const bool wr = (L15 < 8);                   // unique (j, bl) writer
    const float wlin = jv ? W_lin[j] : 0.f;
    float zw[4], zb[4];                          // scaled W_ih, bias
    #pragma unroll
    for (int r = 0; r < 4; ++r) {
        const float s = (r == 2) ? LOG2E2 : -LOG2E;
        zw[r] = jv ? s * W_ih[r * H + j] : 0.f;
        zb[r] = jv ? s * (b_ih[r * H + j] + b_hh[r * H + j]) : 0.f;
    }

    // ---- init: zero hb; fill XT from global x (coalesced in t) ----
    for (int i = tid; i < 2 * BW * KP; i += NTHR)
        ((_Float16*)hb)[i] = (_Float16)0.f;
    for (int i = tid; i < TT * BW; i += NTHR) {
        const int bb = i >> 10, t = i & 1023;
        XT[t][bb] = x[(size_t)(b0 + bb) * TT + t];
    }
    if (tid < 2 * BW) ((float*)&XT[TT][0])[tid] = 0.f;   // pad rows

    float c2 = 0.f;        // scaled cell state: 2*log2e*c
    float hlast = 0.f;
    __syncthreads();

    float xt_cur = XT[0][bl];          // x for step 0
    const bool lo = (sel == 0);

    #pragma unroll 1
    for (int tbase = 0; tbase < TT; tbase += 2) {
        #pragma unroll
        for (int half = 0; half < 2; ++half) {
            const int t = tbase + half;
            const _Float16* hp = &hb[half][bl][0];        // cur buffer
            _Float16*       np = &hb[half ^ 1][bl][0];    // next buffer

            // ---- B fragments: plain reads, k 0..31 and 32..63 ----
            const f16x8 B0 = *(const f16x8*)(hp + kq * 8);
            const f16x8 B1 = *(const f16x8*)(hp + 32 + kq * 8);

            // ---- C-init: gx for this lane's unit (exact f32, off-chain) ----
            f32x4 zc;
            #pragma unroll
            for (int r = 0; r < 4; ++r)
                zc[r] = __builtin_fmaf(zw[r], xt_cur, zb[r]);

            // ---- 4 MFMAs: two independent 2-deep chains ----
            f32x4 a0 = __builtin_amdgcn_mfma_f32_16x16x32_f16(A[0][0], B0, zc, 0, 0, 0);
            f32x4 a1 = __builtin_amdgcn_mfma_f32_16x16x32_f16(A[1][0], B0, zc, 0, 0, 0);
            a0 = __builtin_amdgcn_mfma_f32_16x16x32_f16(A[0][1], B1, a0, 0, 0, 0);
            a1 = __builtin_amdgcn_mfma_f32_16x16x32_f16(A[1][1], B1, a1, 0, 0, 0);

            // prefetch x for next step (off the critical chain)
            const float xt_nxt = XT[t + 1][bl];

            // ---- select this lane's accumulator (tile t0 vs t0+1) ----
            const float gi = lo ? a0[0] : a1[0];
            const float gf = lo ? a0[1] : a1[1];
            const float gg = lo ? a0[2] : a1[2];
            const float go = lo ? a0[3] : a1[3];

            // ---- fused epilogue (exp2-only), scaled-c2 form ----
            const float Ei = __builtin_amdgcn_exp2f(gi);
            const float Ef = __builtin_amdgcn_exp2f(gf);
            const float Eg = __builtin_amdgcn_exp2f(gg);
            const float Eo = __builtin_amdgcn_exp2f(go);
            const float P  = (1.0f + Ei) * (1.0f + Eg);
            const float Q2 = __builtin_fmaf(LOG2E2, Ef, LOG2E2);    // 2λ(1+Ef)
            const float num = __builtin_fmaf(c2, P, (Eg - 1.0f) * Q2);
            const float PQ  = P * (1.0f + Ef);
            c2 = num * __builtin_amdgcn_rcpf(PQ);
            const float ca = fminf(c2, 80.0f);
            const float Ec = __builtin_amdgcn_exp2f(ca);
            const float h  = (Ec - 1.0f) *
                __builtin_amdgcn_rcpf((1.0f + Eo) * (1.0f + Ec));
            hlast = h;

            if (wr) np[j] = (_Float16)h;   // pads self-zero (zero A + zero zc)
            __syncthreads();
            xt_cur = xt_nxt;
        }
    }

    // ---- head: out[b] = b_lin + sum_j W_lin[j] * h[j][b] ----
    if (jv && wr) redH[j][bl] = wlin * hlast;
    __syncthreads();
    if (tid < BW) {
        float s = b_lin[0];
        #pragma unroll 10
        for (int jj = 0; jj < H; ++jj) s += redH[jj][tid];
        out[b0 + tid] = s;
    }
}

extern "C" void kernel_launch(void* const* d_in, const int* in_sizes, int n_in,
                              void* d_out, int out_size, void* d_ws, size_t ws_size,
                              hipStream_t stream) {
    const float* x     = (const float*)d_in[0];
    const float* W_ih  = (const float*)d_in[1];
    const float* W_hh  = (const float*)d_in[2];
    const float* b_ih  = (const float*)d_in[3];
    const float* b_hh  = (const float*)d_in[4];
    const float* W_lin = (const float*)d_in[5];
    const float* b_lin = (const float*)d_in[6];
    float* out = (float*)d_out;

    dim3 grid(BATCH / BW);    // 512 blocks -> 2 co-resident per CU
    dim3 block(NTHR);         // 7 waves
    lstm_kernel<<<grid, block, 0, stream>>>(x, W_ih, W_hh, b_ih, b_hh,
                                            W_lin, b_lin, out);
}

// Round 10
// 350.052 us; speedup vs baseline: 1.5376x; 1.3207x over previous
//
#include <hip/hip_runtime.h>

// LSTM B=2048, T=1024, H=50. Round 23: R18 + barrier-path/chain micro-trims.
//  - R18 skeleton unchanged: 7 waves, BW=8, 1 block/CU, chained split-K MFMA,
//    zc C-operand init (exact f32 gx), exp2-only epilogue, scaled c2.
//  - Trim 1: x-prefetch reads hoisted to the TOP of each 2-step iteration
//    (x(tbase+1), x(tbase+2) issued together with the first B-reads). In R18
//    the XT[t+1] read issued after the MFMAs; its ~120cy latency could land
//    on the lgkmcnt(0) drain before s_barrier (pure barrier-arrival tax).
//    Also halves x-read issue count (fusable to ds_read2_b32).
//  - Trim 2: epilogue tail shortened: Ro = rcp(1+Eo) precomputed right after
//    Eo (off the carried chain); h = ((Ec-1)*Ro) * rcp(1+Ec) removes the
//    (1+Eo)*(1+Ec) mul from the post-Ec dependency path (~4cy/step).
//  - Wave-count map (R13..R22): 4w=670cy-eq, 16w=350, 8w(4x2)=319, 7w=297,
//    14w(7x2)=457 -> 7-wave single block is the chain/issue balance point.

#define H     50
#define TT    1024
#define BATCH 2048
#define BW    8
#define NTHR  448     // 7 waves
#define KP    80      // f16 per hb row (40-word stride, measured conflict-free)

typedef float    f32x4 __attribute__((ext_vector_type(4)));
typedef _Float16 f16x8 __attribute__((ext_vector_type(8)));

__global__ __launch_bounds__(NTHR, 1) void lstm_kernel(
    const float* __restrict__ x,      // [B, T]
    const float* __restrict__ W_ih,   // [200]
    const float* __restrict__ W_hh,   // [200, 50]
    const float* __restrict__ b_ih,   // [200]
    const float* __restrict__ b_hh,   // [200]
    const float* __restrict__ W_lin,  // [50]
    const float* __restrict__ b_lin,  // [1]
    float* __restrict__ out)          // [B]
{
    __shared__ _Float16 hb[2][BW][KP];    // h^T, double-buffered
    __shared__ float    XT[TT + 2][BW];   // x per (t, b), +2 pad rows
    __shared__ float    redH[H][BW];      // head reduction

    const int tid  = threadIdx.x;
    const int wave = tid >> 6;
    const int lane = tid & 63;
    const int L15  = lane & 15;
    const int kq   = lane >> 4;
    const int bl   = L15 & 7;
    const int b0   = blockIdx.x * BW;

    const int t0 = 2 * wave;              // tiles t0, t0+1 (wave 6: 12,13)

    const float LOG2E  = 1.4426950408889634f;
    const float LOG2E2 = 2.8853900817779268f;

    // ---- A fragments: scaled permuted W_hh rows (k 0..49 only), f16 ----
    f16x8 A[2][2];
    #pragma unroll
    for (int tt = 0; tt < 2; ++tt) {
        const int m  = (t0 + tt) * 16 + L15;  // permuted gate-row n' = 4j+g
        const int jm = m >> 2, gm = m & 3;
        const bool v = (jm < H);
        const float s = (gm == 2) ? LOG2E2 : -LOG2E;
        #pragma unroll
        for (int kf = 0; kf < 2; ++kf) {
            f16x8 vv;
            #pragma unroll
            for (int e = 0; e < 8; ++e) {
                const int k = kf * 32 + kq * 8 + e;
                _Float16 val = (_Float16)0.f;
                if (v && k < H) val = (_Float16)(s * W_hh[(gm * H + jm) * H + k]);
                vv[e] = val;
            }
            A[tt][kf] = vv;
        }
    }

    // ---- this lane's unit + exact f32 x-path coefficients (C-init) ----
    const int  j  = 8 * wave + ((L15 >> 3) << 2) + kq;   // 0..55 (50-55 pad)
    const bool jv = (j < H);
    const float wlin = jv ? W_lin[j] : 0.f;
    float zw[4], zb[4];                                  // scaled W_ih, bias
    #pragma unroll
    for (int r = 0; r < 4; ++r) {
        const float s = (r == 2) ? LOG2E2 : -LOG2E;
        zw[r] = jv ? s * W_ih[r * H + j] : 0.f;
        zb[r] = jv ? s * (b_ih[r * H + j] + b_hh[r * H + j]) : 0.f;
    }

    // ---- init: zero hb; fill XT from global x (coalesced in t) ----
    for (int i = tid; i < 2 * BW * KP; i += NTHR)
        ((_Float16*)hb)[i] = (_Float16)0.f;
    for (int i = tid; i < TT * BW; i += NTHR) {
        const int bb = i >> 10, t = i & 1023;
        XT[t][bb] = x[(size_t)(b0 + bb) * TT + t];
    }
    if (tid < 2 * BW) ((float*)&XT[TT][0])[tid] = 0.f;   // pad rows

    float c2 = 0.f;        // scaled cell state: 2*log2e*c
    float hlast = 0.f;
    __syncthreads();

    float xt_cur = XT[0][bl];          // x for step 0
    const bool lo = (L15 < 8);

    #pragma unroll 1
    for (int tbase = 0; tbase < TT; tbase += 2) {
        // ---- both next-x prefetches issued at iteration top (with the
        //      first B-reads): long-drained before any barrier ----
        const float x1 = XT[tbase + 1][bl];
        const float x2 = XT[tbase + 2][bl];

        #pragma unroll
        for (int half = 0; half < 2; ++half) {
            const _Float16* hp = &hb[half][bl][0];        // cur buffer
            _Float16*       np = &hb[half ^ 1][bl][0];    // next buffer
            const float xh = (half == 0) ? xt_cur : x1;

            // ---- B fragments: plain reads, k 0..31 and 32..63 ----
            const f16x8 B0 = *(const f16x8*)(hp + kq * 8);
            const f16x8 B1 = *(const f16x8*)(hp + 32 + kq * 8);

            // ---- C-init: gx for this lane's unit (exact f32, off-chain) ----
            f32x4 zc;
            #pragma unroll
            for (int r = 0; r < 4; ++r)
                zc[r] = __builtin_fmaf(zw[r], xh, zb[r]);

            // ---- 4 MFMAs: two independent 2-deep chains ----
            f32x4 a0 = __builtin_amdgcn_mfma_f32_16x16x32_f16(A[0][0], B0, zc, 0, 0, 0);
            f32x4 a1 = __builtin_amdgcn_mfma_f32_16x16x32_f16(A[1][0], B0, zc, 0, 0, 0);
            a0 = __builtin_amdgcn_mfma_f32_16x16x32_f16(A[0][1], B1, a0, 0, 0, 0);
            a1 = __builtin_amdgcn_mfma_f32_16x16x32_f16(A[1][1], B1, a1, 0, 0, 0);

            // ---- select this lane's accumulator (tile t0 vs t0+1) ----
            const float gi = lo ? a0[0] : a1[0];
            const float gf = lo ? a0[1] : a1[1];
            const float gg = lo ? a0[2] : a1[2];
            const float go = lo ? a0[3] : a1[3];

            // ---- fused epilogue (exp2-only), scaled-c2, Ro-precompute ----
            const float Ei = __builtin_amdgcn_exp2f(gi);
            const float Ef = __builtin_amdgcn_exp2f(gf);
            const float Eg = __builtin_amdgcn_exp2f(gg);
            const float Eo = __builtin_amdgcn_exp2f(go);
            const float Ro = __builtin_amdgcn_rcpf(1.0f + Eo);      // off-chain
            const float P  = (1.0f + Ei) * (1.0f + Eg);
            const float Q2 = __builtin_fmaf(LOG2E2, Ef, LOG2E2);    // 2λ(1+Ef)
            const float num = __builtin_fmaf(c2, P, (Eg - 1.0f) * Q2);
            const float PQ  = P * (1.0f + Ef);
            c2 = num * __builtin_amdgcn_rcpf(PQ);
            const float ca = fminf(c2, 80.0f);
            const float Ec = __builtin_amdgcn_exp2f(ca);
            const float t1 = (Ec - 1.0f) * Ro;
            const float Rc = __builtin_amdgcn_rcpf(1.0f + Ec);
            const float h  = t1 * Rc;
            hlast = h;

            np[j] = (_Float16)h;   // unguarded: pad j -> zero-A slots 50-55
            __syncthreads();
        }
        xt_cur = x2;
    }

    // ---- head: out[b] = b_lin + sum_j W_lin[j] * h[j][b] ----
    if (jv) redH[j][bl] = wlin * hlast;
    __syncthreads();
    if (tid < BW) {
        float s = b_lin[0];
        #pragma unroll 10
        for (int jj = 0; jj < H; ++jj) s += redH[jj][tid];
        out[b0 + tid] = s;
    }
}

extern "C" void kernel_launch(void* const* d_in, const int* in_sizes, int n_in,
                              void* d_out, int out_size, void* d_ws, size_t ws_size,
                              hipStream_t stream) {
    const float* x     = (const float*)d_in[0];
    const float* W_ih  = (const float*)d_in[1];
    const float* W_hh  = (const float*)d_in[2];
    const float* b_ih  = (const float*)d_in[3];
    const float* b_hh  = (const float*)d_in[4];
    const float* W_lin = (const float*)d_in[5];
    const float* b_lin = (const float*)d_in[6];
    float* out = (float*)d_out;

    dim3 grid(BATCH / BW);    // 256 blocks, 1 per CU
    dim3 block(NTHR);         // 7 waves
    lstm_kernel<<<grid, block, 0, stream>>>(x, W_ih, W_hh, b_ih, b_hh,
                                            W_lin, b_lin, out);
}

// Round 11
// 333.240 us; speedup vs baseline: 1.6152x; 1.0504x over previous
//
#include <hip/hip_runtime.h>

// LSTM B=2048, T=1024, H=50. Round 24: restore R18 verbatim — the measured
// best (333.4 us harness, ~297 us dispatch). R23's two micro-trims both
// regressed (+20 cy/step): hoisted XT reads sat ahead of B0/B1 in the
// in-order lgkm queue (deeper drain before MFMA), and the split rcp added
// a serial trans issue. This structure is the balance point of a fully
// mapped landscape (R13-R23):
//   wave-count map (cy/step-eq): 1w=1570, 4w=770, 4wx2blk=700, 7w=700,
//   7wx2blk=1000, 2-barrier interleave=1380, bpermute-no-barrier=1570.
// Step floor = ds_read expose(~120) + chained MFMA(~130) + epilogue(~70-100)
// + write/drain(~60) + barrier+skew(~150-250) ~= 700cy; 1024 steps @2.4GHz
// ~= 300us. All pipes <50%: serial-latency floor, not a counter roofline.
//
// Structure: 7 waves, BW=8, 1 block/CU, grid=256. Wave w owns permuted
// gate-row tiles 2w,2w+1 (rows n'=4j+g). Lane (kq,L15): unit
// j = 8w + 4*(L15>>3) + kq, batch bl = L15&7. A = scaled W_hh' f16 in VGPRs
// (i,f,o rows x -log2e; g rows x +2log2e -> exp2-only epilogue).
// zc C-operand init carries the exact-f32 gx = W_ih*x+b path (per-lane;
// discarded accumulator rows are don't-care). Chained split-K MFMA pairs.
// Cell state pre-scaled: c2 = 2*log2e*c. One barrier per step; x2 unrolled
// halves for static double-buffer addressing; pad units (>=50) self-zero.

#define H     50
#define TT    1024
#define BATCH 2048
#define BW    8
#define NTHR  448     // 7 waves
#define KP    80      // f16 per hb row (40-word stride, measured conflict-free)

typedef float    f32x4 __attribute__((ext_vector_type(4)));
typedef _Float16 f16x8 __attribute__((ext_vector_type(8)));

__global__ __launch_bounds__(NTHR, 1) void lstm_kernel(
    const float* __restrict__ x,      // [B, T]
    const float* __restrict__ W_ih,   // [200]
    const float* __restrict__ W_hh,   // [200, 50]
    const float* __restrict__ b_ih,   // [200]
    const float* __restrict__ b_hh,   // [200]
    const float* __restrict__ W_lin,  // [50]
    const float* __restrict__ b_lin,  // [1]
    float* __restrict__ out)          // [B]
{
    __shared__ _Float16 hb[2][BW][KP];    // h^T, double-buffered
    __shared__ float    XT[TT + 2][BW];   // x per (t, b), +2 pad rows
    __shared__ float    redH[H][BW];      // head reduction

    const int tid  = threadIdx.x;
    const int wave = tid >> 6;
    const int lane = tid & 63;
    const int L15  = lane & 15;
    const int kq   = lane >> 4;
    const int bl   = L15 & 7;
    const int b0   = blockIdx.x * BW;

    const int t0 = 2 * wave;              // tiles t0, t0+1 (wave 6: 12,13)

    const float LOG2E  = 1.4426950408889634f;
    const float LOG2E2 = 2.8853900817779268f;

    // ---- A fragments: scaled permuted W_hh rows (k 0..49 only), f16 ----
    f16x8 A[2][2];
    #pragma unroll
    for (int tt = 0; tt < 2; ++tt) {
        const int m  = (t0 + tt) * 16 + L15;  // permuted gate-row n' = 4j+g
        const int jm = m >> 2, gm = m & 3;
        const bool v = (jm < H);
        const float s = (gm == 2) ? LOG2E2 : -LOG2E;
        #pragma unroll
        for (int kf = 0; kf < 2; ++kf) {
            f16x8 vv;
            #pragma unroll
            for (int e = 0; e < 8; ++e) {
                const int k = kf * 32 + kq * 8 + e;
                _Float16 val = (_Float16)0.f;
                if (v && k < H) val = (_Float16)(s * W_hh[(gm * H + jm) * H + k]);
                vv[e] = val;
            }
            A[tt][kf] = vv;
        }
    }

    // ---- this lane's unit + exact f32 x-path coefficients (C-init) ----
    const int  j  = 8 * wave + ((L15 >> 3) << 2) + kq;   // 0..55 (50-55 pad)
    const bool jv = (j < H);
    const float wlin = jv ? W_lin[j] : 0.f;
    float zw[4], zb[4];                                  // scaled W_ih, bias
    #pragma unroll
    for (int r = 0; r < 4; ++r) {
        const float s = (r == 2) ? LOG2E2 : -LOG2E;
        zw[r] = jv ? s * W_ih[r * H + j] : 0.f;
        zb[r] = jv ? s * (b_ih[r * H + j] + b_hh[r * H + j]) : 0.f;
    }

    // ---- init: zero hb; fill XT from global x (coalesced in t) ----
    for (int i = tid; i < 2 * BW * KP; i += NTHR)
        ((_Float16*)hb)[i] = (_Float16)0.f;
    for (int i = tid; i < TT * BW; i += NTHR) {
        const int bb = i >> 10, t = i & 1023;
        XT[t][bb] = x[(size_t)(b0 + bb) * TT + t];
    }
    if (tid < 2 * BW) ((float*)&XT[TT][0])[tid] = 0.f;   // pad rows for prefetch

    float c2 = 0.f;        // scaled cell state: 2*log2e*c
    float hlast = 0.f;
    __syncthreads();

    float xt_cur = XT[0][bl];          // x for step 0
    const bool lo = (L15 < 8);

    #pragma unroll 1
    for (int tbase = 0; tbase < TT; tbase += 2) {
        #pragma unroll
        for (int half = 0; half < 2; ++half) {
            const int t = tbase + half;
            const _Float16* hp = &hb[half][bl][0];        // cur buffer
            _Float16*       np = &hb[half ^ 1][bl][0];    // next buffer

            // ---- B fragments: plain reads, k 0..31 and 32..63 ----
            const f16x8 B0 = *(const f16x8*)(hp + kq * 8);
            const f16x8 B1 = *(const f16x8*)(hp + 32 + kq * 8);

            // ---- C-init: gx for this lane's unit (exact f32, off-chain) ----
            f32x4 zc;
            #pragma unroll
            for (int r = 0; r < 4; ++r)
                zc[r] = __builtin_fmaf(zw[r], xt_cur, zb[r]);

            // ---- 4 MFMAs: two independent 2-deep chains (R13 form) ----
            f32x4 a0 = __builtin_amdgcn_mfma_f32_16x16x32_f16(A[0][0], B0, zc, 0, 0, 0);
            f32x4 a1 = __builtin_amdgcn_mfma_f32_16x16x32_f16(A[1][0], B0, zc, 0, 0, 0);
            a0 = __builtin_amdgcn_mfma_f32_16x16x32_f16(A[0][1], B1, a0, 0, 0, 0);
            a1 = __builtin_amdgcn_mfma_f32_16x16x32_f16(A[1][1], B1, a1, 0, 0, 0);

            // prefetch x for next step (off the critical chain)
            const float xt_nxt = XT[t + 1][bl];

            // ---- select this lane's accumulator (tile t0 vs t0+1) ----
            const float gi = lo ? a0[0] : a1[0];
            const float gf = lo ? a0[1] : a1[1];
            const float gg = lo ? a0[2] : a1[2];
            const float go = lo ? a0[3] : a1[3];

            // ---- fused epilogue (exp2-only), scaled-c2 form ----
            const float Ei = __builtin_amdgcn_exp2f(gi);
            const float Ef = __builtin_amdgcn_exp2f(gf);
            const float Eg = __builtin_amdgcn_exp2f(gg);
            const float Eo = __builtin_amdgcn_exp2f(go);
            const float P  = (1.0f + Ei) * (1.0f + Eg);
            const float Q2 = __builtin_fmaf(LOG2E2, Ef, LOG2E2);    // 2λ(1+Ef)
            const float num = __builtin_fmaf(c2, P, (Eg - 1.0f) * Q2);
            const float PQ  = P * (1.0f + Ef);
            c2 = num * __builtin_amdgcn_rcpf(PQ);
            const float ca = fminf(c2, 80.0f);
            const float Ec = __builtin_amdgcn_exp2f(ca);
            const float h  = (Ec - 1.0f) *
                __builtin_amdgcn_rcpf((1.0f + Eo) * (1.0f + Ec));
            hlast = h;

            np[j] = (_Float16)h;   // unguarded: pad j -> zero-A slots 50-55
            __syncthreads();
            xt_cur = xt_nxt;
        }
    }

    // ---- head: out[b] = b_lin + sum_j W_lin[j] * h[j][b] ----
    if (jv) redH[j][bl] = wlin * hlast;
    __syncthreads();
    if (tid < BW) {
        float s = b_lin[0];
        #pragma unroll 10
        for (int jj = 0; jj < H; ++jj) s += redH[jj][tid];
        out[b0 + tid] = s;
    }
}

extern "C" void kernel_launch(void* const* d_in, const int* in_sizes, int n_in,
                              void* d_out, int out_size, void* d_ws, size_t ws_size,
                              hipStream_t stream) {
    const float* x     = (const float*)d_in[0];
    const float* W_ih  = (const float*)d_in[1];
    const float* W_hh  = (const float*)d_in[2];
    const float* b_ih  = (const float*)d_in[3];
    const float* b_hh  = (const float*)d_in[4];
    const float* W_lin = (const float*)d_in[5];
    const float* b_lin = (const float*)d_in[6];
    float* out = (float*)d_out;

    dim3 grid(BATCH / BW);    // 256 blocks, 1 per CU
    dim3 block(NTHR);         // 7 waves
    lstm_kernel<<<grid, block, 0, stream>>>(x, W_ih, W_hh, b_ih, b_hh,
                                            W_lin, b_lin, out);
}